// Round 11
// baseline (2597.534 us; speedup 1.0000x reference)
//
#include <hip/hip_runtime.h>
#include <hip/hip_bf16.h>
#include <hip/hip_fp16.h>

#define N_NODES 100000
#define N_EDGES 1600000
#define HEADS 4
#define CHN 32
#define HID 128
#define LAYERS 4
#define IN_F 8
#define ED_F 6
#define OUT_F 256
#define NEG_SLOPE 0.2f

typedef _Float16 f16x8 __attribute__((ext_vector_type(8)));
typedef _Float16 f16x4 __attribute__((ext_vector_type(4)));
typedef _Float16 h2 __attribute__((ext_vector_type(2)));
typedef float f32x4 __attribute__((ext_vector_type(4)));

#if defined(__has_builtin)
#if __has_builtin(__builtin_amdgcn_fdot2)
#define HAVE_FDOT2 1
#endif
#endif

__device__ __forceinline__ float elu_f(float x) {
    return x > 0.f ? x : expm1f(x);
}

__device__ __forceinline__ h2 bith2(float f) {
    union { float f; h2 h; } u; u.f = f; return u.h;
}

__device__ __forceinline__ h2 absh2(h2 a) {
    union { h2 h; unsigned int u; } x; x.h = a; x.u &= 0x7FFF7FFFu; return x.h;
}

__device__ __forceinline__ float fdot2f(h2 a, h2 b, float c) {
#ifdef HAVE_FDOT2
    return __builtin_amdgcn_fdot2(a, b, c, false);
#else
    return fmaf((float)a[1], (float)b[1], fmaf((float)a[0], (float)b[0], c));
#endif
}

// ---------------- CSR build ----------------

__global__ void hist_kernel(const int* __restrict__ dst, int* __restrict__ fill) {
    int e = blockIdx.x * blockDim.x + threadIdx.x;
    if (e < N_EDGES) atomicAdd(&fill[dst[e]], 1);
}

__global__ void scan1_kernel(const int* __restrict__ cnt, int* __restrict__ bsum) {
    __shared__ int sd[256];
    int t = threadIdx.x;
    int base = blockIdx.x * 1024 + t * 4;
    int s = 0;
#pragma unroll
    for (int j = 0; j < 4; ++j) {
        int i = base + j;
        if (i < N_NODES) s += cnt[i];
    }
    sd[t] = s;
    for (int off = 128; off > 0; off >>= 1) {
        __syncthreads();
        if (t < off) sd[t] += sd[t + off];
    }
    if (t == 0) bsum[blockIdx.x] = sd[0];
}

__global__ void scan2_kernel(int* __restrict__ bsum, int* __restrict__ rowptr, int nb) {
    int run = 0;
    for (int b = 0; b < nb; ++b) {
        int v = bsum[b];
        bsum[b] = run;
        run += v;
    }
    rowptr[N_NODES] = run;
}

__global__ void scan3_kernel(const int* __restrict__ cnt, const int* __restrict__ bsum,
                             int* __restrict__ rowptr) {
    __shared__ int sd[256];
    int t = threadIdx.x;
    int base = blockIdx.x * 1024 + t * 4;
    int v[4];
#pragma unroll
    for (int j = 0; j < 4; ++j) {
        int i = base + j;
        v[j] = (i < N_NODES) ? cnt[i] : 0;
    }
    int s = v[0] + v[1] + v[2] + v[3];
    sd[t] = s;
    __syncthreads();
    for (int off = 1; off < 256; off <<= 1) {
        int xv = (t >= off) ? sd[t - off] : 0;
        __syncthreads();
        sd[t] += xv;
        __syncthreads();
    }
    int excl = sd[t] - s + bsum[blockIdx.x];
    int pre = 0;
#pragma unroll
    for (int j = 0; j < 4; ++j) {
        int i = base + j;
        if (i < N_NODES) rowptr[i] = excl + pre;
        pre += v[j];
    }
}

// csr stores BYTE offsets: x = src*HID*2 (f16 row), y = eid*32 (splatted f16 eattr row)
__global__ void fill_kernel(const int* __restrict__ src, const int* __restrict__ dst,
                            const int* __restrict__ rowptr, int* __restrict__ fill,
                            int2* __restrict__ csr) {
    int e = blockIdx.x * blockDim.x + threadIdx.x;
    if (e >= N_EDGES) return;
    int d = dst[e];
    int p = rowptr[d] + atomicAdd(&fill[d], 1);
    csr[p] = make_int2(src[e] * (HID * 2), e * 32);
}

// eattr -> splatted f16 [E][16]: f16[2d] = f16[2d+1] = eattr[e][d] (d<6), 0 pad
__global__ void ecvt_kernel(const float* __restrict__ eattr, __half* __restrict__ ea16) {
    int gid = blockIdx.x * blockDim.x + threadIdx.x;
    if (gid >= N_EDGES * 16) return;
    int e = gid >> 4, j = gid & 15, d = j >> 1;
    float v = (d < ED_F) ? eattr[e * ED_F + d] : 0.f;
    ea16[gid] = __float2half_rn(v);
}

// loop_attr mean, splatted f16 [N][16]
__global__ void lattr_kernel(const int* __restrict__ rowptr, const int2* __restrict__ csr,
                             const float* __restrict__ eattr, __half* __restrict__ lat16) {
    int gid = blockIdx.x * blockDim.x + threadIdx.x;
    if (gid >= N_NODES * 16) return;
    int n = gid >> 4;
    int d = (gid & 15) >> 1;
    float s = 0.f;
    if (d < ED_F) {
        int rp0 = rowptr[n], rp1 = rowptr[n + 1];
        for (int p = rp0; p < rp1; ++p) {
            int eid = csr[p].y >> 5;
            s += eattr[(size_t)eid * ED_F + d];
        }
        int deg = rp1 - rp0;
        s /= (float)(deg > 0 ? deg : 1);
    }
    lat16[gid] = __float2half_rn(s);
}

// ---------------- weight conversion ----------------
// wbt: 5 panels [256][128] f16 XOR-swizzled (GEMM B operands)

__global__ void convw_kernel(const float* __restrict__ W_l, const float* __restrict__ W_r,
                             const float* __restrict__ W_out, __half* __restrict__ wbt) {
    int gid = blockIdx.x * blockDim.x + threadIdx.x;
    if (gid >= 5 * 256 * 128) return;
    int b = gid >> 15;
    int idx = gid & 32767;
    int n = idx >> 7, k = idx & 127;
    float val;
    if (b < 4)
        val = (n < HID) ? W_l[b * HID * HID + k * HID + n]
                        : W_r[b * HID * HID + k * HID + (n - HID)];
    else
        val = W_out[k * OUT_F + n];
    int boff = n * 256 + ((k * 2) ^ ((n & 7) << 4));
    *(__half*)((char*)wbt + (size_t)b * 65536 + boff) = __float2half_rn(val);
}

// edge-kernel panels per layer: We16 [6][128] f16, att06 [128] f16 (0.6*att), att04 [128] f16
__global__ void convwe_kernel(const float* __restrict__ W_e, const float* __restrict__ att,
                              __half* __restrict__ wep) {
    int gid = blockIdx.x * blockDim.x + threadIdx.x;
    if (gid >= LAYERS * 8 * 128) return;
    int l = gid >> 10;
    int idx = gid & 1023;
    int row = idx >> 7, c = idx & 127;
    float val;
    if (row < 6) val = W_e[l * ED_F * HID + row * HID + c];
    else if (row == 6) val = 0.6f * att[l * HID + c];
    else val = 0.4f * att[l * HID + c];
    wep[gid] = __float2half_rn(val);
}

// ---------------- input MLP: h0 = ELU(x @ W_in + b_in) ----------------

__global__ void in_kernel(const float* __restrict__ x, const float* __restrict__ Wi,
                          const float* __restrict__ bi, float* __restrict__ h0) {
    int gid = blockIdx.x * blockDim.x + threadIdx.x;
    if (gid >= N_NODES * HID) return;
    int n = gid >> 7, j = gid & 127;
    float acc = bi[j];
#pragma unroll
    for (int k = 0; k < IN_F; ++k) acc = fmaf(x[n * IN_F + k], Wi[k * HID + j], acc);
    h0[gid] = elu_f(acc);
}

// ---------------- MFMA GEMM ----------------
// MODE 0: cols 0..127 -> xl16 (f16, +bl); cols 128..255 -> xr16 (f16, +br)
// MODE 1: all 256 cols -> outp (f32, +b_out)

#define LDS_B_OFF 16384

template <int MODE>
__global__ __launch_bounds__(256, 2) void gemm_kernel(
    const float* __restrict__ A, const __half* __restrict__ Bt,
    const float* __restrict__ bias0, const float* __restrict__ bias1,
    __half* __restrict__ xl16, __half* __restrict__ xr16, float* __restrict__ outp) {
    __shared__ __align__(16) unsigned char smem[81920];
    int t = threadIdx.x;
    int row0 = blockIdx.x * 64;

#pragma unroll
    for (int it = 0; it < 8; ++it) {
        int idx = it * 256 + t;
        int r = idx >> 5;
        int k4 = (idx & 31) << 2;
        float4 hv = *(const float4*)(A + (size_t)(row0 + r) * HID + k4);
        f16x4 p;
        p[0] = (_Float16)hv.x; p[1] = (_Float16)hv.y;
        p[2] = (_Float16)hv.z; p[3] = (_Float16)hv.w;
        *(f16x4*)(smem + r * 256 + ((k4 * 2) ^ ((r & 7) << 4))) = p;
    }
#pragma unroll
    for (int it = 0; it < 16; ++it) {
        int off = (it * 256 + t) * 16;
        *(float4*)(smem + LDS_B_OFF + off) = *(const float4*)((const char*)Bt + off);
    }
    __syncthreads();

    int wave = t >> 6;
    int lane = t & 63;
    int lc = lane & 15, lr = lane >> 4;
    int cbase = wave * 64;

    f32x4 acc[4][4];
#pragma unroll
    for (int i = 0; i < 4; ++i)
#pragma unroll
        for (int j = 0; j < 4; ++j) acc[i][j] = (f32x4){0.f, 0.f, 0.f, 0.f};

#pragma unroll
    for (int kk = 0; kk < 4; ++kk) {
        int kb = kk * 64 + lr * 16;
        f16x8 av[4], bv[4];
#pragma unroll
        for (int rt = 0; rt < 4; ++rt) {
            int r = rt * 16 + lc;
            av[rt] = *(const f16x8*)(smem + r * 256 + (kb ^ ((r & 7) << 4)));
        }
#pragma unroll
        for (int ct = 0; ct < 4; ++ct) {
            int c = cbase + ct * 16 + lc;
            bv[ct] = *(const f16x8*)(smem + LDS_B_OFF + c * 256 + (kb ^ ((c & 7) << 4)));
        }
#pragma unroll
        for (int rt = 0; rt < 4; ++rt)
#pragma unroll
            for (int ct = 0; ct < 4; ++ct)
                acc[rt][ct] = __builtin_amdgcn_mfma_f32_16x16x32_f16(av[rt], bv[ct],
                                                                     acc[rt][ct], 0, 0, 0);
    }

#pragma unroll
    for (int ct = 0; ct < 4; ++ct) {
        int col = cbase + ct * 16 + lc;
        float bv;
        if (MODE == 0) bv = (col < HID) ? bias0[col] : bias1[col - HID];
        else bv = bias0[col];
#pragma unroll
        for (int rt = 0; rt < 4; ++rt) {
#pragma unroll
            for (int q = 0; q < 4; ++q) {
                int node = row0 + rt * 16 + lr * 4 + q;
                if (node < N_NODES) {
                    float val = acc[rt][ct][q] + bv;
                    if (MODE == 0) {
                        if (col < HID)
                            xl16[(size_t)node * HID + col] = __float2half_rn(val);
                        else
                            xr16[(size_t)node * HID + (col - HID)] = __float2half_rn(val);
                    } else {
                        outp[(size_t)node * OUT_F + col] = val;
                    }
                }
            }
        }
    }
}

// ---------------- fused edge kernel: 4 edges/wave, 8 ch/lane, packed f16 ------------
// One wave per dst node. Quarter-wave q (lanes 16q..16q+15) processes item i = 4r+q;
// item 0 = self-loop, i>=1 -> csr[rp0+i-1]. Lane ql owns channels 8*ql..8*ql+7.
// leaky(s) = 0.6s + 0.4|s| (exact for slope 0.2); score via v_dot2_f32_f16.

struct Slot {
    float4 er0;  // splats d0..d3
    float2 er1;  // splats d4,d5
    float4 xv;   // 8 f16: xl[src] channels c0..c0+7
};

__device__ __forceinline__ void slot_issue(Slot& s, int i, int total, int rp0,
                                           const int2* __restrict__ csr,
                                           const char* eab, const char* lat16v,
                                           const char* xlb, int vbytes) {
    i = min(i, total - 1);
    const char* eb;
    const char* xb;
    if (i == 0) {
        eb = lat16v;
        xb = xlb + (size_t)vbytes;
    } else {
        int2 se = csr[rp0 + i - 1];
        eb = eab + (size_t)se.y;
        xb = xlb + (size_t)se.x;
    }
    s.er0 = *(const float4*)eb;
    s.er1 = *(const float2*)(eb + 16);
    s.xv = *(const float4*)xb;
}

__device__ __forceinline__ void slot_consume(const Slot& sl, int i, int total,
                                             const h2 w2[6][4], const h2* a06, const h2* a04,
                                             const h2* xr2, float& denom, float* acc) {
    h2 es0 = bith2(sl.er0.x), es1 = bith2(sl.er0.y), es2 = bith2(sl.er0.z);
    h2 es3 = bith2(sl.er0.w), es4 = bith2(sl.er1.x), es5 = bith2(sl.er1.y);
    h2 xl2[4];
    xl2[0] = bith2(sl.xv.x); xl2[1] = bith2(sl.xv.y);
    xl2[2] = bith2(sl.xv.z); xl2[3] = bith2(sl.xv.w);
    float t = 0.f;
#pragma unroll
    for (int p = 0; p < 4; ++p) {
        h2 sp = xl2[p] + xr2[p];
        sp += es0 * w2[0][p];
        sp += es1 * w2[1][p];
        sp += es2 * w2[2][p];
        sp += es3 * w2[3][p];
        sp += es4 * w2[4][p];
        sp += es5 * w2[5][p];
        t = fdot2f(sp, a06[p], t);
        t = fdot2f(absh2(sp), a04[p], t);
    }
    // head reduce: 4 lanes x 8 ch = 32 channels (within quarter-wave)
    t += __shfl_xor(t, 1);
    t += __shfl_xor(t, 2);
    float ex = __expf(t);
    ex = (i < total) ? ex : 0.f;
    denom += ex;
#pragma unroll
    for (int p = 0; p < 4; ++p) {
        acc[2 * p]     = fmaf((float)xl2[p][0], ex, acc[2 * p]);
        acc[2 * p + 1] = fmaf((float)xl2[p][1], ex, acc[2 * p + 1]);
    }
}

// NOTE: launch_bounds 2nd arg (64, 8): on this toolchain it acts as the resident-wave
// target — (64,4) in R10 pinned occupancy to 43% and cost +30 µs. Keep 8.
__global__ __launch_bounds__(64, 8) void edge_kernel(
    const __half* __restrict__ xl, const __half* __restrict__ xr16,
    float* __restrict__ h,            // in-place: read row v (residual), write row v
    const int* __restrict__ rowptr, const int2* __restrict__ csr,
    const __half* __restrict__ ea16, const __half* __restrict__ lat16,
    const __half* __restrict__ wep,   // [6][128] We16 | [128] 0.6att | [128] 0.4att
    const float* __restrict__ bias_l, const float* __restrict__ lnw,
    const float* __restrict__ lnb) {
    int v = blockIdx.x;
    int lane = threadIdx.x;
    int q = lane >> 4;
    int ql = lane & 15;
    int c0 = ql * 8;

    h2 w2[6][4];
#pragma unroll
    for (int d = 0; d < 6; ++d) {
        float4 wv = *(const float4*)(wep + d * HID + c0);
        w2[d][0] = bith2(wv.x); w2[d][1] = bith2(wv.y);
        w2[d][2] = bith2(wv.z); w2[d][3] = bith2(wv.w);
    }
    h2 a06[4], a04[4], xr2[4];
    {
        float4 a6 = *(const float4*)(wep + 6 * HID + c0);
        a06[0] = bith2(a6.x); a06[1] = bith2(a6.y); a06[2] = bith2(a6.z); a06[3] = bith2(a6.w);
        float4 a4 = *(const float4*)(wep + 7 * HID + c0);
        a04[0] = bith2(a4.x); a04[1] = bith2(a4.y); a04[2] = bith2(a4.z); a04[3] = bith2(a4.w);
        float4 xv = *(const float4*)(xr16 + (size_t)v * HID + c0);
        xr2[0] = bith2(xv.x); xr2[1] = bith2(xv.y); xr2[2] = bith2(xv.z); xr2[3] = bith2(xv.w);
    }

    int rp0 = rowptr[v], rp1 = rowptr[v + 1];
    int total = (rp1 - rp0) + 1;
    int R = (total + 3) >> 2;

    const char* xlb = (const char*)xl + (size_t)c0 * 2;
    const char* eab = (const char*)ea16;
    const char* lat16v = (const char*)lat16 + (size_t)v * 32;
    int vbytes = v * (HID * 2);

    float denom = 0.f;
    float acc[8] = {0.f, 0.f, 0.f, 0.f, 0.f, 0.f, 0.f, 0.f};

    Slot sA, sB;
    slot_issue(sA, q, total, rp0, csr, eab, lat16v, xlb, vbytes);
    if (R > 1) slot_issue(sB, 4 + q, total, rp0, csr, eab, lat16v, xlb, vbytes);
    int r = 0;
    for (; r + 2 <= R; r += 2) {
        slot_consume(sA, 4 * r + q, total, w2, a06, a04, xr2, denom, acc);
        if (r + 2 < R) slot_issue(sA, 4 * (r + 2) + q, total, rp0, csr, eab, lat16v, xlb, vbytes);
        slot_consume(sB, 4 * (r + 1) + q, total, w2, a06, a04, xr2, denom, acc);
        if (r + 3 < R) slot_issue(sB, 4 * (r + 3) + q, total, rp0, csr, eab, lat16v, xlb, vbytes);
    }
    if (r < R) slot_consume(sA, 4 * r + q, total, w2, a06, a04, xr2, denom, acc);

    // combine quarters
    denom += __shfl_xor(denom, 16);
    denom += __shfl_xor(denom, 32);
#pragma unroll
    for (int c = 0; c < 8; ++c) {
        acc[c] += __shfl_xor(acc[c], 16);
        acc[c] += __shfl_xor(acc[c], 32);
    }
    float rd = 1.f / denom;

    // ---- epilogue: bias + residual + LayerNorm + ELU (8 channels per lane)
    float4 res0 = *(const float4*)(h + (size_t)v * HID + c0);
    float4 res1 = *(const float4*)(h + (size_t)v * HID + c0 + 4);
    float4 bv0 = *(const float4*)(bias_l + c0);
    float4 bv1 = *(const float4*)(bias_l + c0 + 4);
    float y[8];
    y[0] = acc[0] * rd + bv0.x + res0.x;
    y[1] = acc[1] * rd + bv0.y + res0.y;
    y[2] = acc[2] * rd + bv0.z + res0.z;
    y[3] = acc[3] * rd + bv0.w + res0.w;
    y[4] = acc[4] * rd + bv1.x + res1.x;
    y[5] = acc[5] * rd + bv1.y + res1.y;
    y[6] = acc[6] * rd + bv1.z + res1.z;
    y[7] = acc[7] * rd + bv1.w + res1.w;
    float s = 0.f, sq = 0.f;
#pragma unroll
    for (int c = 0; c < 8; ++c) {
        s += y[c];
        sq = fmaf(y[c], y[c], sq);
    }
#pragma unroll
    for (int off = 1; off < 16; off <<= 1) {
        s += __shfl_xor(s, off);
        sq += __shfl_xor(sq, off);
    }
    float mu = s * (1.f / HID);
    float var = sq * (1.f / HID) - mu * mu;
    float rstd = rsqrtf(var + 1e-5f);
    float4 wv0 = *(const float4*)(lnw + c0);
    float4 wv1 = *(const float4*)(lnw + c0 + 4);
    float4 lb0 = *(const float4*)(lnb + c0);
    float4 lb1 = *(const float4*)(lnb + c0 + 4);
    if (q == 0) {
        float4 o0, o1;
        o0.x = elu_f((y[0] - mu) * rstd * wv0.x + lb0.x);
        o0.y = elu_f((y[1] - mu) * rstd * wv0.y + lb0.y);
        o0.z = elu_f((y[2] - mu) * rstd * wv0.z + lb0.z);
        o0.w = elu_f((y[3] - mu) * rstd * wv0.w + lb0.w);
        o1.x = elu_f((y[4] - mu) * rstd * wv1.x + lb1.x);
        o1.y = elu_f((y[5] - mu) * rstd * wv1.y + lb1.y);
        o1.z = elu_f((y[6] - mu) * rstd * wv1.z + lb1.z);
        o1.w = elu_f((y[7] - mu) * rstd * wv1.w + lb1.w);
        *(float4*)(h + (size_t)v * HID + c0) = o0;
        *(float4*)(h + (size_t)v * HID + c0 + 4) = o1;
    }
}

// ---------------- launch ----------------

extern "C" void kernel_launch(void* const* d_in, const int* in_sizes, int n_in,
                              void* d_out, int out_size, void* d_ws, size_t ws_size,
                              hipStream_t stream) {
    const float* x     = (const float*)d_in[0];
    const int*   ei    = (const int*)d_in[1];
    const float* eattr = (const float*)d_in[2];
    const float* W_in  = (const float*)d_in[3];
    const float* b_in  = (const float*)d_in[4];
    const float* W_l   = (const float*)d_in[5];
    const float* b_l   = (const float*)d_in[6];
    const float* W_r   = (const float*)d_in[7];
    const float* b_r   = (const float*)d_in[8];
    const float* W_e   = (const float*)d_in[9];
    const float* att   = (const float*)d_in[10];
    const float* bias  = (const float*)d_in[11];
    const float* lnw   = (const float*)d_in[12];
    const float* lnb   = (const float*)d_in[13];
    const float* W_out = (const float*)d_in[14];
    const float* b_out = (const float*)d_in[15];
    float* out = (float*)d_out;

    // workspace: h | xl16 | lat16 | rowptr | fill | csr | bsum | wbt | wep
    float*  h     = (float*)d_ws;
    __half* xl    = (__half*)(h + (size_t)N_NODES * HID);
    __half* lat16 = xl + (size_t)N_NODES * HID;                  // N*16 f16 splats
    int* rowptr   = (int*)(lat16 + (size_t)N_NODES * 16);
    int* fill     = rowptr + (N_NODES + 4);
    int2* csr     = (int2*)(fill + N_NODES);
    int* bsum     = (int*)(csr + N_EDGES);
    __half* wbt   = (__half*)(bsum + 128);        // 5 x 65536 B GEMM panels
    __half* wep   = wbt + (size_t)5 * 32768;      // L x 8 x 128 f16 edge panels

    // d_out (102.4 MB) partition: xr16 f16 (25.6 MB) | ea16 splats [E][16] f16 (51.2 MB)
    __half* xr16 = (__half*)out;
    __half* ea16 = xr16 + (size_t)N_NODES * HID;

    const int* srcv = ei;
    const int* dstv = ei + N_EDGES;

    hipMemsetAsync(fill, 0, N_NODES * sizeof(int), stream);
    hist_kernel<<<(N_EDGES + 255) / 256, 256, 0, stream>>>(dstv, fill);
    int nb = (N_NODES + 1023) / 1024;
    scan1_kernel<<<nb, 256, 0, stream>>>(fill, bsum);
    scan2_kernel<<<1, 1, 0, stream>>>(bsum, rowptr, nb);
    scan3_kernel<<<nb, 256, 0, stream>>>(fill, bsum, rowptr);
    hipMemsetAsync(fill, 0, N_NODES * sizeof(int), stream);
    fill_kernel<<<(N_EDGES + 255) / 256, 256, 0, stream>>>(srcv, dstv, rowptr, fill, csr);
    ecvt_kernel<<<(N_EDGES * 16 + 255) / 256, 256, 0, stream>>>(eattr, ea16);
    lattr_kernel<<<(N_NODES * 16 + 255) / 256, 256, 0, stream>>>(rowptr, csr, eattr, lat16);

    convw_kernel<<<(5 * 256 * 128 + 255) / 256, 256, 0, stream>>>(W_l, W_r, W_out, wbt);
    convwe_kernel<<<(LAYERS * 8 * 128 + 255) / 256, 256, 0, stream>>>(W_e, att, wep);
    in_kernel<<<(N_NODES * HID) / 256, 256, 0, stream>>>(x, W_in, b_in, h);

    int gemm_grid = (N_NODES + 63) / 64;
    for (int l = 0; l < LAYERS; ++l) {
        gemm_kernel<0><<<gemm_grid, 256, 0, stream>>>(
            h, wbt + (size_t)l * 32768, b_l + (size_t)l * HID, b_r + (size_t)l * HID,
            xl, xr16, nullptr);
        edge_kernel<<<N_NODES, 64, 0, stream>>>(
            xl, xr16, h, rowptr, csr, ea16, lat16,
            wep + (size_t)l * 1024,
            bias + (size_t)l * HID, lnw + (size_t)l * HID, lnb + (size_t)l * HID);
    }

    gemm_kernel<1><<<gemm_grid, 256, 0, stream>>>(
        h, wbt + (size_t)4 * 32768, b_out, nullptr, nullptr, nullptr, out);
}

// Round 12
// 1062.831 us; speedup vs baseline: 2.4440x; 2.4440x over previous
//
#include <hip/hip_runtime.h>
#include <hip/hip_bf16.h>
#include <hip/hip_fp16.h>

#define N_NODES 100000
#define N_EDGES 1600000
#define HEADS 4
#define CHN 32
#define HID 128
#define LAYERS 4
#define IN_F 8
#define ED_F 6
#define OUT_F 256
#define NEG_SLOPE 0.2f

typedef _Float16 f16x8 __attribute__((ext_vector_type(8)));
typedef _Float16 f16x4 __attribute__((ext_vector_type(4)));
typedef _Float16 h2 __attribute__((ext_vector_type(2)));
typedef float f32x4 __attribute__((ext_vector_type(4)));

#if defined(__has_builtin)
#if __has_builtin(__builtin_amdgcn_fdot2)
#define HAVE_FDOT2 1
#endif
#endif

__device__ __forceinline__ float elu_f(float x) {
    return x > 0.f ? x : expm1f(x);
}

__device__ __forceinline__ h2 bith2(float f) {
    union { float f; h2 h; } u; u.f = f; return u.h;
}

__device__ __forceinline__ float dot6(h2 e01, h2 e23, h2 e45, const h2* w) {
#ifdef HAVE_FDOT2
    return __builtin_amdgcn_fdot2(e45, w[2],
           __builtin_amdgcn_fdot2(e23, w[1],
           __builtin_amdgcn_fdot2(e01, w[0], 0.f, false), false), false);
#else
    float s = (float)e01[0] * (float)w[0][0];
    s = fmaf((float)e01[1], (float)w[0][1], s);
    s = fmaf((float)e23[0], (float)w[1][0], s);
    s = fmaf((float)e23[1], (float)w[1][1], s);
    s = fmaf((float)e45[0], (float)w[2][0], s);
    s = fmaf((float)e45[1], (float)w[2][1], s);
    return s;
#endif
}

// ---------------- CSR build ----------------

__global__ void hist_kernel(const int* __restrict__ dst, int* __restrict__ fill) {
    int e = blockIdx.x * blockDim.x + threadIdx.x;
    if (e < N_EDGES) atomicAdd(&fill[dst[e]], 1);
}

__global__ void scan1_kernel(const int* __restrict__ cnt, int* __restrict__ bsum) {
    __shared__ int sd[256];
    int t = threadIdx.x;
    int base = blockIdx.x * 1024 + t * 4;
    int s = 0;
#pragma unroll
    for (int j = 0; j < 4; ++j) {
        int i = base + j;
        if (i < N_NODES) s += cnt[i];
    }
    sd[t] = s;
    for (int off = 128; off > 0; off >>= 1) {
        __syncthreads();
        if (t < off) sd[t] += sd[t + off];
    }
    if (t == 0) bsum[blockIdx.x] = sd[0];
}

// parallel single-block exclusive scan over block sums (nb <= 256)
__global__ void scan2_kernel(int* __restrict__ bsum, int* __restrict__ rowptr, int nb) {
    __shared__ int sd[256];
    int t = threadIdx.x;
    int v = (t < nb) ? bsum[t] : 0;
    sd[t] = v;
    __syncthreads();
    for (int off = 1; off < 256; off <<= 1) {
        int x = (t >= off) ? sd[t - off] : 0;
        __syncthreads();
        sd[t] += x;
        __syncthreads();
    }
    if (t < nb) bsum[t] = sd[t] - v;          // exclusive block offset
    if (t == 0) rowptr[N_NODES] = sd[255];    // grand total
}

__global__ void scan3_kernel(const int* __restrict__ cnt, const int* __restrict__ bsum,
                             int* __restrict__ rowptr) {
    __shared__ int sd[256];
    int t = threadIdx.x;
    int base = blockIdx.x * 1024 + t * 4;
    int v[4];
#pragma unroll
    for (int j = 0; j < 4; ++j) {
        int i = base + j;
        v[j] = (i < N_NODES) ? cnt[i] : 0;
    }
    int s = v[0] + v[1] + v[2] + v[3];
    sd[t] = s;
    __syncthreads();
    for (int off = 1; off < 256; off <<= 1) {
        int xv = (t >= off) ? sd[t - off] : 0;
        __syncthreads();
        sd[t] += xv;
        __syncthreads();
    }
    int excl = sd[t] - s + bsum[blockIdx.x];
    int pre = 0;
#pragma unroll
    for (int j = 0; j < 4; ++j) {
        int i = base + j;
        if (i < N_NODES) rowptr[i] = excl + pre;
        pre += v[j];
    }
}

// csr stores BYTE offsets: x = src*HID*2 (f16 row), y = eid*16 (padded f16 eattr row)
__global__ void fill_kernel(const int* __restrict__ src, const int* __restrict__ dst,
                            const int* __restrict__ rowptr, int* __restrict__ fill,
                            int2* __restrict__ csr) {
    int e = blockIdx.x * blockDim.x + threadIdx.x;
    if (e >= N_EDGES) return;
    int d = dst[e];
    int p = rowptr[d] + atomicAdd(&fill[d], 1);
    csr[p] = make_int2(src[e] * (HID * 2), e * 16);
}

// eattr -> padded f16 [E][8]
__global__ void ecvt_kernel(const float* __restrict__ eattr, __half* __restrict__ ea16) {
    int gid = blockIdx.x * blockDim.x + threadIdx.x;
    if (gid >= N_EDGES * 8) return;
    int e = gid >> 3, d = gid & 7;
    float v = (d < ED_F) ? eattr[e * ED_F + d] : 0.f;
    ea16[gid] = __float2half_rn(v);
}

// loop_attr = mean of incoming edge_attr per node, padded f16 [N][8]
__global__ void lattr_kernel(const int* __restrict__ rowptr, const int2* __restrict__ csr,
                             const float* __restrict__ eattr, __half* __restrict__ lat16) {
    int gid = blockIdx.x * blockDim.x + threadIdx.x;
    if (gid >= N_NODES * 8) return;
    int n = gid >> 3;
    int d = gid & 7;
    float s = 0.f;
    if (d < ED_F) {
        int rp0 = rowptr[n], rp1 = rowptr[n + 1];
        for (int p = rp0; p < rp1; ++p) {
            int eid = csr[p].y >> 4;
            s += eattr[(size_t)eid * ED_F + d];
        }
        int deg = rp1 - rp0;
        s /= (float)(deg > 0 ? deg : 1);
    }
    lat16[gid] = __float2half_rn(s);
}

// ---------------- weight conversion: 5 panels [256][128] f16 XOR-swizzled ----------

__global__ void convw_kernel(const float* __restrict__ W_l, const float* __restrict__ W_r,
                             const float* __restrict__ W_out, __half* __restrict__ wbt) {
    int gid = blockIdx.x * blockDim.x + threadIdx.x;
    if (gid >= 5 * 256 * 128) return;
    int b = gid >> 15;
    int idx = gid & 32767;
    int n = idx >> 7, k = idx & 127;
    float val;
    if (b < 4)
        val = (n < HID) ? W_l[b * HID * HID + k * HID + n]
                        : W_r[b * HID * HID + k * HID + (n - HID)];
    else
        val = W_out[k * OUT_F + n];
    int boff = n * 256 + ((k * 2) ^ ((n & 7) << 4));
    *(__half*)((char*)wbt + (size_t)b * 65536 + boff) = __float2half_rn(val);
}

// ---------------- input MLP: h16 = ELU(x @ W_in + b_in), stored f16 ----------------

__global__ void in_kernel(const float* __restrict__ x, const float* __restrict__ Wi,
                          const float* __restrict__ bi, __half* __restrict__ h16) {
    int gid = blockIdx.x * blockDim.x + threadIdx.x;
    if (gid >= N_NODES * HID) return;
    int n = gid >> 7, j = gid & 127;
    float acc = bi[j];
#pragma unroll
    for (int k = 0; k < IN_F; ++k) acc = fmaf(x[n * IN_F + k], Wi[k * HID + j], acc);
    h16[gid] = __float2half_rn(elu_f(acc));
}

// ---------------- MFMA GEMM: A is f16 [M][128] ----------------
// MODE 0: cols 0..127 -> xl16 (f16, +bl); cols 128..255 -> xr (f32, +br)
// MODE 1: all 256 cols -> outp (f32, +b_out)

#define LDS_B_OFF 16384

template <int MODE>
__global__ __launch_bounds__(256, 2) void gemm_kernel(
    const __half* __restrict__ A16, const __half* __restrict__ Bt,
    const float* __restrict__ bias0, const float* __restrict__ bias1,
    __half* __restrict__ xl16, float* __restrict__ xr_out, float* __restrict__ outp) {
    __shared__ __align__(16) unsigned char smem[81920];
    int t = threadIdx.x;
    int row0 = blockIdx.x * 64;

    // stage A: 64 rows x 256 B f16, swizzled LDS writes (16 KB)
#pragma unroll
    for (int it = 0; it < 4; ++it) {
        int idx = it * 256 + t;
        int r = idx >> 4;
        int kb = (idx & 15) * 16;
        f16x8 p = *(const f16x8*)((const char*)A16 + (size_t)(row0 + r) * 256 + kb);
        *(f16x8*)(smem + r * 256 + (kb ^ ((r & 7) << 4))) = p;
    }
    // stage B: pre-swizzled global -> linear LDS copy (65536 B)
#pragma unroll
    for (int it = 0; it < 16; ++it) {
        int off = (it * 256 + t) * 16;
        *(float4*)(smem + LDS_B_OFF + off) = *(const float4*)((const char*)Bt + off);
    }
    __syncthreads();

    int wave = t >> 6;
    int lane = t & 63;
    int lc = lane & 15, lr = lane >> 4;
    int cbase = wave * 64;

    f32x4 acc[4][4];
#pragma unroll
    for (int i = 0; i < 4; ++i)
#pragma unroll
        for (int j = 0; j < 4; ++j) acc[i][j] = (f32x4){0.f, 0.f, 0.f, 0.f};

#pragma unroll
    for (int kk = 0; kk < 4; ++kk) {
        int kb = kk * 64 + lr * 16;
        f16x8 av[4], bv[4];
#pragma unroll
        for (int rt = 0; rt < 4; ++rt) {
            int r = rt * 16 + lc;
            av[rt] = *(const f16x8*)(smem + r * 256 + (kb ^ ((r & 7) << 4)));
        }
#pragma unroll
        for (int ct = 0; ct < 4; ++ct) {
            int c = cbase + ct * 16 + lc;
            bv[ct] = *(const f16x8*)(smem + LDS_B_OFF + c * 256 + (kb ^ ((c & 7) << 4)));
        }
#pragma unroll
        for (int rt = 0; rt < 4; ++rt)
#pragma unroll
            for (int ct = 0; ct < 4; ++ct)
                acc[rt][ct] = __builtin_amdgcn_mfma_f32_16x16x32_f16(av[rt], bv[ct],
                                                                     acc[rt][ct], 0, 0, 0);
    }

    // epilogue (C/D: col = lane&15, row = (lane>>4)*4 + q)
#pragma unroll
    for (int ct = 0; ct < 4; ++ct) {
        int col = cbase + ct * 16 + lc;
        float bv;
        if (MODE == 0) bv = (col < HID) ? bias0[col] : bias1[col - HID];
        else bv = bias0[col];
#pragma unroll
        for (int rt = 0; rt < 4; ++rt) {
#pragma unroll
            for (int q = 0; q < 4; ++q) {
                int node = row0 + rt * 16 + lr * 4 + q;
                if (node < N_NODES) {
                    float val = acc[rt][ct][q] + bv;
                    if (MODE == 0) {
                        if (col < HID)
                            xl16[(size_t)node * HID + col] = __float2half_rn(val);
                        else
                            xr_out[(size_t)node * HID + (col - HID)] = val;
                    } else {
                        outp[(size_t)node * OUT_F + col] = val;
                    }
                }
            }
        }
    }
}

// ---------------- fused edge kernel: 2 edges per wave, 4 channels per lane ----------
// (R9 body — 32 VGPR at (64,8), proven 154 us.) h residual read/write now f16.

struct Slot {
    float4 er;   // 8 f16: eattr row (padded)
    float2 xv;   // 4 f16: xl[src] channels c0..c0+3
};

__device__ __forceinline__ void slot_issue(Slot& s, int i, int total, int rp0,
                                           const int2* __restrict__ csr,
                                           const char* eab, const char* lat16v,
                                           const char* xlb, int vbytes) {
    i = min(i, total - 1);
    const char* eb;
    const char* xb;
    if (i == 0) {
        eb = lat16v;
        xb = xlb + (size_t)vbytes;
    } else {
        int2 se = csr[rp0 + i - 1];
        eb = eab + (size_t)se.y;
        xb = xlb + (size_t)se.x;
    }
    s.er = *(const float4*)eb;
    s.xv = *(const float2*)xb;
}

__device__ __forceinline__ void slot_consume(const Slot& sl, int i, int total,
                                             const h2 we_h2[4][3], const float* attv,
                                             const float* xrv,
                                             float& denom, float* acc) {
    h2 e01 = bith2(sl.er.x), e23 = bith2(sl.er.y), e45 = bith2(sl.er.z);
    h2 x01 = bith2(sl.xv.x), x23 = bith2(sl.xv.y);
    float xf[4];
    xf[0] = (float)x01[0]; xf[1] = (float)x01[1];
    xf[2] = (float)x23[0]; xf[3] = (float)x23[1];
    float t = 0.f;
#pragma unroll
    for (int c = 0; c < 4; ++c) {
        float ea = dot6(e01, e23, e45, we_h2[c]);
        float m = xf[c] + xrv[c] + ea;
        m = m > 0.f ? m : NEG_SLOPE * m;
        t = fmaf(m, attv[c], t);
    }
    // head reduce: 8 lanes x 4 ch = 32 channels (within half-wave)
    t += __shfl_xor(t, 1);
    t += __shfl_xor(t, 2);
    t += __shfl_xor(t, 4);
    float ex = __expf(t);
    ex = (i < total) ? ex : 0.f;
    denom += ex;
#pragma unroll
    for (int c = 0; c < 4; ++c) acc[c] = fmaf(ex, xf[c], acc[c]);
}

// NOTE: 2nd launch_bounds arg = VGPR budget 256/n on this toolchain.
// (64,8) -> 32 VGPR: R9 body fits exactly; bigger bodies spill (R11: 2 GB scratch traffic).
__global__ __launch_bounds__(64, 8) void edge_kernel(
    const __half* __restrict__ xl, const float* __restrict__ xr,
    __half* __restrict__ h16,         // in-place: read row v (residual), write row v
    const int* __restrict__ rowptr, const int2* __restrict__ csr,
    const __half* __restrict__ ea16, const __half* __restrict__ lat16,
    const float* __restrict__ We, const float* __restrict__ att,
    const float* __restrict__ bias_l, const float* __restrict__ lnw,
    const float* __restrict__ lnb) {
    int v = blockIdx.x;
    int lane = threadIdx.x;
    int half = lane >> 5;
    int hl = lane & 31;
    int c0 = hl * 4;

    h2 we_h2[4][3];
#pragma unroll
    for (int c = 0; c < 4; ++c)
#pragma unroll
        for (int d = 0; d < 3; ++d) {
            h2 w;
            w[0] = (_Float16)We[(2 * d) * HID + c0 + c];
            w[1] = (_Float16)We[(2 * d + 1) * HID + c0 + c];
            we_h2[c][d] = w;
        }
    float4 at4 = *(const float4*)(att + c0);
    float attv[4] = {at4.x, at4.y, at4.z, at4.w};
    float4 xr4 = *(const float4*)(xr + (size_t)v * HID + c0);
    float xrv[4] = {xr4.x, xr4.y, xr4.z, xr4.w};

    int rp0 = rowptr[v], rp1 = rowptr[v + 1];
    int total = (rp1 - rp0) + 1;
    int R = (total + 1) >> 1;

    const char* xlb = (const char*)xl + (size_t)c0 * 2;
    const char* eab = (const char*)ea16;
    const char* lat16v = (const char*)lat16 + (size_t)v * 16;
    int vbytes = v * (HID * 2);

    float denom = 0.f;
    float acc[4] = {0.f, 0.f, 0.f, 0.f};

    Slot sA, sB;
    slot_issue(sA, half, total, rp0, csr, eab, lat16v, xlb, vbytes);
    if (R > 1) slot_issue(sB, 2 + half, total, rp0, csr, eab, lat16v, xlb, vbytes);
    int r = 0;
    for (; r + 2 <= R; r += 2) {
        slot_consume(sA, 2 * r + half, total, we_h2, attv, xrv, denom, acc);
        if (r + 2 < R) slot_issue(sA, 2 * (r + 2) + half, total, rp0, csr, eab, lat16v, xlb, vbytes);
        slot_consume(sB, 2 * (r + 1) + half, total, we_h2, attv, xrv, denom, acc);
        if (r + 3 < R) slot_issue(sB, 2 * (r + 3) + half, total, rp0, csr, eab, lat16v, xlb, vbytes);
    }
    if (r < R) slot_consume(sA, 2 * r + half, total, we_h2, attv, xrv, denom, acc);

    // combine halves
    denom += __shfl_xor(denom, 32);
#pragma unroll
    for (int c = 0; c < 4; ++c) acc[c] += __shfl_xor(acc[c], 32);

    float rd = 1.f / denom;

    // ---- epilogue: bias + residual(f16) + LayerNorm + ELU -> h16
    float2 rb = *(const float2*)(h16 + (size_t)v * HID + c0);
    h2 r01 = bith2(rb.x), r23 = bith2(rb.y);
    float4 bv4 = *(const float4*)(bias_l + c0);
    float y[4];
    y[0] = acc[0] * rd + bv4.x + (float)r01[0];
    y[1] = acc[1] * rd + bv4.y + (float)r01[1];
    y[2] = acc[2] * rd + bv4.z + (float)r23[0];
    y[3] = acc[3] * rd + bv4.w + (float)r23[1];
    float s = y[0] + y[1] + y[2] + y[3];
    float sq = fmaf(y[0], y[0], fmaf(y[1], y[1], fmaf(y[2], y[2], y[3] * y[3])));
#pragma unroll
    for (int off = 1; off < 32; off <<= 1) {
        s += __shfl_xor(s, off);
        sq += __shfl_xor(sq, off);
    }
    float mu = s * (1.f / HID);
    float var = sq * (1.f / HID) - mu * mu;
    float rstd = rsqrtf(var + 1e-5f);
    float4 wv4 = *(const float4*)(lnw + c0);
    float4 lb4 = *(const float4*)(lnb + c0);
    if (half == 0) {
        f16x4 o;
        o[0] = (_Float16)elu_f((y[0] - mu) * rstd * wv4.x + lb4.x);
        o[1] = (_Float16)elu_f((y[1] - mu) * rstd * wv4.y + lb4.y);
        o[2] = (_Float16)elu_f((y[2] - mu) * rstd * wv4.z + lb4.z);
        o[3] = (_Float16)elu_f((y[3] - mu) * rstd * wv4.w + lb4.w);
        *(f16x4*)(h16 + (size_t)v * HID + c0) = o;
    }
}

// ---------------- launch ----------------

extern "C" void kernel_launch(void* const* d_in, const int* in_sizes, int n_in,
                              void* d_out, int out_size, void* d_ws, size_t ws_size,
                              hipStream_t stream) {
    const float* x     = (const float*)d_in[0];
    const int*   ei    = (const int*)d_in[1];
    const float* eattr = (const float*)d_in[2];
    const float* W_in  = (const float*)d_in[3];
    const float* b_in  = (const float*)d_in[4];
    const float* W_l   = (const float*)d_in[5];
    const float* b_l   = (const float*)d_in[6];
    const float* W_r   = (const float*)d_in[7];
    const float* b_r   = (const float*)d_in[8];
    const float* W_e   = (const float*)d_in[9];
    const float* att   = (const float*)d_in[10];
    const float* bias  = (const float*)d_in[11];
    const float* lnw   = (const float*)d_in[12];
    const float* lnb   = (const float*)d_in[13];
    const float* W_out = (const float*)d_in[14];
    const float* b_out = (const float*)d_in[15];
    float* out = (float*)d_out;

    // workspace: h16 | lat16 | rowptr | fill | csr | bsum | wbt
    __half* h16   = (__half*)d_ws;
    __half* lat16 = h16 + (size_t)N_NODES * HID;                 // N*8 f16
    int* rowptr   = (int*)(lat16 + (size_t)N_NODES * 8);
    int* fill     = rowptr + (N_NODES + 4);
    int2* csr     = (int2*)(fill + N_NODES);
    int* bsum     = (int*)(csr + N_EDGES);
    __half* wbt   = (__half*)(bsum + 256);   // 5 x 65536 B f16 GEMM panels

    // d_out (102.4 MB): xr f32 (51.2) | xl16 (25.6) | ea16 [E][8] f16 (25.6)
    float*  xr   = out;
    __half* xl   = (__half*)(out + (size_t)N_NODES * HID);
    __half* ea16 = xl + (size_t)N_NODES * HID;

    const int* srcv = ei;
    const int* dstv = ei + N_EDGES;

    hipMemsetAsync(fill, 0, N_NODES * sizeof(int), stream);
    hist_kernel<<<(N_EDGES + 255) / 256, 256, 0, stream>>>(dstv, fill);
    int nb = (N_NODES + 1023) / 1024;
    scan1_kernel<<<nb, 256, 0, stream>>>(fill, bsum);
    scan2_kernel<<<1, 256, 0, stream>>>(bsum, rowptr, nb);
    scan3_kernel<<<nb, 256, 0, stream>>>(fill, bsum, rowptr);
    hipMemsetAsync(fill, 0, N_NODES * sizeof(int), stream);
    fill_kernel<<<(N_EDGES + 255) / 256, 256, 0, stream>>>(srcv, dstv, rowptr, fill, csr);
    ecvt_kernel<<<(N_EDGES * 8 + 255) / 256, 256, 0, stream>>>(eattr, ea16);
    lattr_kernel<<<(N_NODES * 8 + 255) / 256, 256, 0, stream>>>(rowptr, csr, eattr, lat16);

    convw_kernel<<<(5 * 256 * 128 + 255) / 256, 256, 0, stream>>>(W_l, W_r, W_out, wbt);
    in_kernel<<<(N_NODES * HID) / 256, 256, 0, stream>>>(x, W_in, b_in, h16);

    int gemm_grid = (N_NODES + 63) / 64;
    for (int l = 0; l < LAYERS; ++l) {
        gemm_kernel<0><<<gemm_grid, 256, 0, stream>>>(
            h16, wbt + (size_t)l * 32768, b_l + (size_t)l * HID, b_r + (size_t)l * HID,
            xl, xr, nullptr);
        edge_kernel<<<N_NODES, 64, 0, stream>>>(
            xl, xr, h16, rowptr, csr, ea16, lat16,
            W_e + (size_t)l * ED_F * HID, att + (size_t)l * HEADS * CHN,
            bias + (size_t)l * HID, lnw + (size_t)l * HID, lnb + (size_t)l * HID);
    }

    gemm_kernel<1><<<gemm_grid, 256, 0, stream>>>(
        h16, wbt + (size_t)4 * 32768, b_out, nullptr, nullptr, nullptr, out);
}

// Round 13
// 925.398 us; speedup vs baseline: 2.8069x; 1.1485x over previous
//
#include <hip/hip_runtime.h>
#include <hip/hip_bf16.h>
#include <hip/hip_fp16.h>

#define N_NODES 100000
#define N_EDGES 1600000
#define HEADS 4
#define CHN 32
#define HID 128
#define LAYERS 4
#define IN_F 8
#define ED_F 6
#define OUT_F 256
#define NEG_SLOPE 0.2f

#define NT_GEMM ((N_NODES + 63) / 64)   // 1563 row-tiles
#define GRID_GEMM 512                    // 2 blocks/CU, persistent

typedef _Float16 f16x8 __attribute__((ext_vector_type(8)));
typedef _Float16 f16x4 __attribute__((ext_vector_type(4)));
typedef _Float16 h2 __attribute__((ext_vector_type(2)));
typedef float f32x4 __attribute__((ext_vector_type(4)));

#if defined(__has_builtin)
#if __has_builtin(__builtin_amdgcn_fdot2)
#define HAVE_FDOT2 1
#endif
#endif

__device__ __forceinline__ float elu_f(float x) {
    return x > 0.f ? x : expm1f(x);
}

__device__ __forceinline__ h2 bith2(float f) {
    union { float f; h2 h; } u; u.f = f; return u.h;
}

__device__ __forceinline__ float dot6(h2 e01, h2 e23, h2 e45, const h2* w) {
#ifdef HAVE_FDOT2
    return __builtin_amdgcn_fdot2(e45, w[2],
           __builtin_amdgcn_fdot2(e23, w[1],
           __builtin_amdgcn_fdot2(e01, w[0], 0.f, false), false), false);
#else
    float s = (float)e01[0] * (float)w[0][0];
    s = fmaf((float)e01[1], (float)w[0][1], s);
    s = fmaf((float)e23[0], (float)w[1][0], s);
    s = fmaf((float)e23[1], (float)w[1][1], s);
    s = fmaf((float)e45[0], (float)w[2][0], s);
    s = fmaf((float)e45[1], (float)w[2][1], s);
    return s;
#endif
}

// ---------------- CSR build ----------------

__global__ void hist_kernel(const int* __restrict__ dst, int* __restrict__ fill) {
    int e = blockIdx.x * blockDim.x + threadIdx.x;
    if (e < N_EDGES) atomicAdd(&fill[dst[e]], 1);
}

__global__ void scan1_kernel(const int* __restrict__ cnt, int* __restrict__ bsum) {
    __shared__ int sd[256];
    int t = threadIdx.x;
    int base = blockIdx.x * 1024 + t * 4;
    int s = 0;
#pragma unroll
    for (int j = 0; j < 4; ++j) {
        int i = base + j;
        if (i < N_NODES) s += cnt[i];
    }
    sd[t] = s;
    for (int off = 128; off > 0; off >>= 1) {
        __syncthreads();
        if (t < off) sd[t] += sd[t + off];
    }
    if (t == 0) bsum[blockIdx.x] = sd[0];
}

// parallel single-block exclusive scan over block sums (nb <= 256)
__global__ void scan2_kernel(int* __restrict__ bsum, int* __restrict__ rowptr, int nb) {
    __shared__ int sd[256];
    int t = threadIdx.x;
    int v = (t < nb) ? bsum[t] : 0;
    sd[t] = v;
    __syncthreads();
    for (int off = 1; off < 256; off <<= 1) {
        int x = (t >= off) ? sd[t - off] : 0;
        __syncthreads();
        sd[t] += x;
        __syncthreads();
    }
    if (t < nb) bsum[t] = sd[t] - v;
    if (t == 0) rowptr[N_NODES] = sd[255];
}

__global__ void scan3_kernel(const int* __restrict__ cnt, const int* __restrict__ bsum,
                             int* __restrict__ rowptr) {
    __shared__ int sd[256];
    int t = threadIdx.x;
    int base = blockIdx.x * 1024 + t * 4;
    int v[4];
#pragma unroll
    for (int j = 0; j < 4; ++j) {
        int i = base + j;
        v[j] = (i < N_NODES) ? cnt[i] : 0;
    }
    int s = v[0] + v[1] + v[2] + v[3];
    sd[t] = s;
    __syncthreads();
    for (int off = 1; off < 256; off <<= 1) {
        int xv = (t >= off) ? sd[t - off] : 0;
        __syncthreads();
        sd[t] += xv;
        __syncthreads();
    }
    int excl = sd[t] - s + bsum[blockIdx.x];
    int pre = 0;
#pragma unroll
    for (int j = 0; j < 4; ++j) {
        int i = base + j;
        if (i < N_NODES) rowptr[i] = excl + pre;
        pre += v[j];
    }
}

// csr BYTE offsets: x = src*512 (xlr f16 row of 256), y = eid*16 (padded f16 eattr row)
__global__ void fill_kernel(const int* __restrict__ src, const int* __restrict__ dst,
                            const int* __restrict__ rowptr, int* __restrict__ fill,
                            int2* __restrict__ csr) {
    int e = blockIdx.x * blockDim.x + threadIdx.x;
    if (e >= N_EDGES) return;
    int d = dst[e];
    int p = rowptr[d] + atomicAdd(&fill[d], 1);
    csr[p] = make_int2(src[e] * 512, e * 16);
}

// eattr -> padded f16 [E][8]
__global__ void ecvt_kernel(const float* __restrict__ eattr, __half* __restrict__ ea16) {
    int gid = blockIdx.x * blockDim.x + threadIdx.x;
    if (gid >= N_EDGES * 8) return;
    int e = gid >> 3, d = gid & 7;
    float v = (d < ED_F) ? eattr[e * ED_F + d] : 0.f;
    ea16[gid] = __float2half_rn(v);
}

// loop_attr = mean of incoming edge_attr per node, padded f16 [N][8]; gathers from ea16
__global__ void lattr_kernel(const int* __restrict__ rowptr, const int2* __restrict__ csr,
                             const __half* __restrict__ ea16, __half* __restrict__ lat16) {
    int gid = blockIdx.x * blockDim.x + threadIdx.x;
    if (gid >= N_NODES * 8) return;
    int n = gid >> 3;
    int d = gid & 7;
    float s = 0.f;
    if (d < ED_F) {
        int rp0 = rowptr[n], rp1 = rowptr[n + 1];
        for (int p = rp0; p < rp1; ++p) {
            int eid = csr[p].y >> 4;
            s += (float)ea16[(size_t)eid * 8 + d];
        }
        int deg = rp1 - rp0;
        s /= (float)(deg > 0 ? deg : 1);
    }
    lat16[gid] = __float2half_rn(s);
}

// ---------------- weight conversion: 5 panels [256][128] f16 XOR-swizzled ----------

__global__ void convw_kernel(const float* __restrict__ W_l, const float* __restrict__ W_r,
                             const float* __restrict__ W_out, __half* __restrict__ wbt) {
    int gid = blockIdx.x * blockDim.x + threadIdx.x;
    if (gid >= 5 * 256 * 128) return;
    int b = gid >> 15;
    int idx = gid & 32767;
    int n = idx >> 7, k = idx & 127;
    float val;
    if (b < 4)
        val = (n < HID) ? W_l[b * HID * HID + k * HID + n]
                        : W_r[b * HID * HID + k * HID + (n - HID)];
    else
        val = W_out[k * OUT_F + n];
    int boff = n * 256 + ((k * 2) ^ ((n & 7) << 4));
    *(__half*)((char*)wbt + (size_t)b * 65536 + boff) = __float2half_rn(val);
}

// ---------------- input MLP: h16 = ELU(x @ W_in + b_in), stored f16 ----------------

__global__ void in_kernel(const float* __restrict__ x, const float* __restrict__ Wi,
                          const float* __restrict__ bi, __half* __restrict__ h16) {
    int gid = blockIdx.x * blockDim.x + threadIdx.x;
    if (gid >= N_NODES * HID) return;
    int n = gid >> 7, j = gid & 127;
    float acc = bi[j];
#pragma unroll
    for (int k = 0; k < IN_F; ++k) acc = fmaf(x[n * IN_F + k], Wi[k * HID + j], acc);
    h16[gid] = __float2half_rn(elu_f(acc));
}

// ---------------- persistent MFMA GEMM: A f16 [M][128], B panel staged ONCE --------
// MODE 0: all 256 cols -> xlr16 f16 [N][256] (+bl cols 0..127, +br cols 128..255)
// MODE 1: all 256 cols -> outp f32 (+b_out)

#define LDS_B_OFF 16384

template <int MODE>
__global__ __launch_bounds__(256, 2) void gemm_kernel(
    const __half* __restrict__ A16, const __half* __restrict__ Bt,
    const float* __restrict__ bias0, const float* __restrict__ bias1,
    __half* __restrict__ xlr16, float* __restrict__ outp) {
    __shared__ __align__(16) unsigned char smem[81920];
    int t = threadIdx.x;

    // stage B once: pre-swizzled global -> linear LDS copy (65536 B)
#pragma unroll
    for (int it = 0; it < 16; ++it) {
        int off = (it * 256 + t) * 16;
        *(float4*)(smem + LDS_B_OFF + off) = *(const float4*)((const char*)Bt + off);
    }

    int wave = t >> 6;
    int lane = t & 63;
    int lc = lane & 15, lr = lane >> 4;
    int cbase = wave * 64;

    for (int tile = blockIdx.x; tile < NT_GEMM; tile += GRID_GEMM) {
        int row0 = tile * 64;
        // stage A: 64 rows x 256 B f16, swizzled LDS writes (16 KB)
#pragma unroll
        for (int it = 0; it < 4; ++it) {
            int idx = it * 256 + t;
            int r = idx >> 4;
            int kb = (idx & 15) * 16;
            f16x8 p = *(const f16x8*)((const char*)A16 + (size_t)(row0 + r) * 256 + kb);
            *(f16x8*)(smem + r * 256 + (kb ^ ((r & 7) << 4))) = p;
        }
        __syncthreads();

        f32x4 acc[4][4];
#pragma unroll
        for (int i = 0; i < 4; ++i)
#pragma unroll
            for (int j = 0; j < 4; ++j) acc[i][j] = (f32x4){0.f, 0.f, 0.f, 0.f};

#pragma unroll
        for (int kk = 0; kk < 4; ++kk) {
            int kb = kk * 64 + lr * 16;
            f16x8 av[4], bv[4];
#pragma unroll
            for (int rt = 0; rt < 4; ++rt) {
                int r = rt * 16 + lc;
                av[rt] = *(const f16x8*)(smem + r * 256 + (kb ^ ((r & 7) << 4)));
            }
#pragma unroll
            for (int ct = 0; ct < 4; ++ct) {
                int c = cbase + ct * 16 + lc;
                bv[ct] = *(const f16x8*)(smem + LDS_B_OFF + c * 256 + (kb ^ ((c & 7) << 4)));
            }
#pragma unroll
            for (int rt = 0; rt < 4; ++rt)
#pragma unroll
                for (int ct = 0; ct < 4; ++ct)
                    acc[rt][ct] = __builtin_amdgcn_mfma_f32_16x16x32_f16(av[rt], bv[ct],
                                                                         acc[rt][ct], 0, 0, 0);
        }
        __syncthreads();   // all waves done reading A-LDS; epilogue is register-only

        // epilogue (C/D: col = lane&15, row = (lane>>4)*4 + q)
#pragma unroll
        for (int ct = 0; ct < 4; ++ct) {
            int col = cbase + ct * 16 + lc;
            float bv;
            if (MODE == 0) bv = (col < HID) ? bias0[col] : bias1[col - HID];
            else bv = bias0[col];
#pragma unroll
            for (int rt = 0; rt < 4; ++rt) {
#pragma unroll
                for (int q = 0; q < 4; ++q) {
                    int node = row0 + rt * 16 + lr * 4 + q;
                    if (node < N_NODES) {
                        float val = acc[rt][ct][q] + bv;
                        if (MODE == 0)
                            xlr16[(size_t)node * 256 + col] = __float2half_rn(val);
                        else
                            outp[(size_t)node * OUT_F + col] = val;
                    }
                }
            }
        }
    }
}

// ---------------- fused edge kernel: 2 edges per wave, 4 channels per lane ----------
// (R9/R12 body — 32 VGPR at (64,8), proven 153 us.) xl/xr merged in xlr16 [N][256] f16.

struct Slot {
    float4 er;   // 8 f16: eattr row (padded)
    float2 xv;   // 4 f16: xl[src] channels c0..c0+3
};

__device__ __forceinline__ void slot_issue(Slot& s, int i, int total, int rp0,
                                           const int2* __restrict__ csr,
                                           const char* eab, const char* lat16v,
                                           const char* xlb, int vbytes) {
    i = min(i, total - 1);
    const char* eb;
    const char* xb;
    if (i == 0) {
        eb = lat16v;
        xb = xlb + (size_t)vbytes;
    } else {
        int2 se = csr[rp0 + i - 1];
        eb = eab + (size_t)se.y;
        xb = xlb + (size_t)se.x;
    }
    s.er = *(const float4*)eb;
    s.xv = *(const float2*)xb;
}

__device__ __forceinline__ void slot_consume(const Slot& sl, int i, int total,
                                             const h2 we_h2[4][3], const float* attv,
                                             const float* xrv,
                                             float& denom, float* acc) {
    h2 e01 = bith2(sl.er.x), e23 = bith2(sl.er.y), e45 = bith2(sl.er.z);
    h2 x01 = bith2(sl.xv.x), x23 = bith2(sl.xv.y);
    float xf[4];
    xf[0] = (float)x01[0]; xf[1] = (float)x01[1];
    xf[2] = (float)x23[0]; xf[3] = (float)x23[1];
    float t = 0.f;
#pragma unroll
    for (int c = 0; c < 4; ++c) {
        float ea = dot6(e01, e23, e45, we_h2[c]);
        float m = xf[c] + xrv[c] + ea;
        m = m > 0.f ? m : NEG_SLOPE * m;
        t = fmaf(m, attv[c], t);
    }
    t += __shfl_xor(t, 1);
    t += __shfl_xor(t, 2);
    t += __shfl_xor(t, 4);
    float ex = __expf(t);
    ex = (i < total) ? ex : 0.f;
    denom += ex;
#pragma unroll
    for (int c = 0; c < 4; ++c) acc[c] = fmaf(ex, xf[c], acc[c]);
}

// NOTE: 2nd launch_bounds arg = VGPR budget 256/n on this toolchain.
// (64,8) -> 32 VGPR: this body fits exactly; bigger bodies spill (R11: 2 GB scratch).
__global__ __launch_bounds__(64, 8) void edge_kernel(
    const __half* __restrict__ xlr16,   // [N][256]: cols 0..127 = xl, 128..255 = xr
    __half* __restrict__ h16,           // in-place residual read + output write
    const int* __restrict__ rowptr, const int2* __restrict__ csr,
    const __half* __restrict__ ea16, const __half* __restrict__ lat16,
    const float* __restrict__ We, const float* __restrict__ att,
    const float* __restrict__ bias_l, const float* __restrict__ lnw,
    const float* __restrict__ lnb) {
    int v = blockIdx.x;
    int lane = threadIdx.x;
    int half = lane >> 5;
    int hl = lane & 31;
    int c0 = hl * 4;

    h2 we_h2[4][3];
#pragma unroll
    for (int c = 0; c < 4; ++c)
#pragma unroll
        for (int d = 0; d < 3; ++d) {
            h2 w;
            w[0] = (_Float16)We[(2 * d) * HID + c0 + c];
            w[1] = (_Float16)We[(2 * d + 1) * HID + c0 + c];
            we_h2[c][d] = w;
        }
    float4 at4 = *(const float4*)(att + c0);
    float attv[4] = {at4.x, at4.y, at4.z, at4.w};
    float xrv[4];
    {
        float2 xraw = *(const float2*)(xlr16 + (size_t)v * 256 + 128 + c0);
        h2 xr01 = bith2(xraw.x), xr23 = bith2(xraw.y);
        xrv[0] = (float)xr01[0]; xrv[1] = (float)xr01[1];
        xrv[2] = (float)xr23[0]; xrv[3] = (float)xr23[1];
    }

    int rp0 = rowptr[v], rp1 = rowptr[v + 1];
    int total = (rp1 - rp0) + 1;
    int R = (total + 1) >> 1;

    const char* xlb = (const char*)xlr16 + (size_t)c0 * 2;
    const char* eab = (const char*)ea16;
    const char* lat16v = (const char*)lat16 + (size_t)v * 16;
    int vbytes = v * 512;

    float denom = 0.f;
    float acc[4] = {0.f, 0.f, 0.f, 0.f};

    Slot sA, sB;
    slot_issue(sA, half, total, rp0, csr, eab, lat16v, xlb, vbytes);
    if (R > 1) slot_issue(sB, 2 + half, total, rp0, csr, eab, lat16v, xlb, vbytes);
    int r = 0;
    for (; r + 2 <= R; r += 2) {
        slot_consume(sA, 2 * r + half, total, we_h2, attv, xrv, denom, acc);
        if (r + 2 < R) slot_issue(sA, 2 * (r + 2) + half, total, rp0, csr, eab, lat16v, xlb, vbytes);
        slot_consume(sB, 2 * (r + 1) + half, total, we_h2, attv, xrv, denom, acc);
        if (r + 3 < R) slot_issue(sB, 2 * (r + 3) + half, total, rp0, csr, eab, lat16v, xlb, vbytes);
    }
    if (r < R) slot_consume(sA, 2 * r + half, total, we_h2, attv, xrv, denom, acc);

    denom += __shfl_xor(denom, 32);
#pragma unroll
    for (int c = 0; c < 4; ++c) acc[c] += __shfl_xor(acc[c], 32);

    float rd = 1.f / denom;

    // ---- epilogue: bias + residual(f16) + LayerNorm + ELU -> h16
    float2 rb = *(const float2*)(h16 + (size_t)v * HID + c0);
    h2 r01 = bith2(rb.x), r23 = bith2(rb.y);
    float4 bv4 = *(const float4*)(bias_l + c0);
    float y[4];
    y[0] = acc[0] * rd + bv4.x + (float)r01[0];
    y[1] = acc[1] * rd + bv4.y + (float)r01[1];
    y[2] = acc[2] * rd + bv4.z + (float)r23[0];
    y[3] = acc[3] * rd + bv4.w + (float)r23[1];
    float s = y[0] + y[1] + y[2] + y[3];
    float sq = fmaf(y[0], y[0], fmaf(y[1], y[1], fmaf(y[2], y[2], y[3] * y[3])));
#pragma unroll
    for (int off = 1; off < 32; off <<= 1) {
        s += __shfl_xor(s, off);
        sq += __shfl_xor(sq, off);
    }
    float mu = s * (1.f / HID);
    float var = sq * (1.f / HID) - mu * mu;
    float rstd = rsqrtf(var + 1e-5f);
    float4 wv4 = *(const float4*)(lnw + c0);
    float4 lb4 = *(const float4*)(lnb + c0);
    if (half == 0) {
        f16x4 o;
        o[0] = (_Float16)elu_f((y[0] - mu) * rstd * wv4.x + lb4.x);
        o[1] = (_Float16)elu_f((y[1] - mu) * rstd * wv4.y + lb4.y);
        o[2] = (_Float16)elu_f((y[2] - mu) * rstd * wv4.z + lb4.z);
        o[3] = (_Float16)elu_f((y[3] - mu) * rstd * wv4.w + lb4.w);
        *(f16x4*)(h16 + (size_t)v * HID + c0) = o;
    }
}

// ---------------- launch ----------------

extern "C" void kernel_launch(void* const* d_in, const int* in_sizes, int n_in,
                              void* d_out, int out_size, void* d_ws, size_t ws_size,
                              hipStream_t stream) {
    const float* x     = (const float*)d_in[0];
    const int*   ei    = (const int*)d_in[1];
    const float* eattr = (const float*)d_in[2];
    const float* W_in  = (const float*)d_in[3];
    const float* b_in  = (const float*)d_in[4];
    const float* W_l   = (const float*)d_in[5];
    const float* b_l   = (const float*)d_in[6];
    const float* W_r   = (const float*)d_in[7];
    const float* b_r   = (const float*)d_in[8];
    const float* W_e   = (const float*)d_in[9];
    const float* att   = (const float*)d_in[10];
    const float* bias  = (const float*)d_in[11];
    const float* lnw   = (const float*)d_in[12];
    const float* lnb   = (const float*)d_in[13];
    const float* W_out = (const float*)d_in[14];
    const float* b_out = (const float*)d_in[15];
    float* out = (float*)d_out;

    // workspace: h16 | lat16 | rowptr | fill | csr | bsum | wbt
    __half* h16   = (__half*)d_ws;
    __half* lat16 = h16 + (size_t)N_NODES * HID;                 // N*8 f16
    int* rowptr   = (int*)(lat16 + (size_t)N_NODES * 8);
    int* fill     = rowptr + (N_NODES + 4);
    int2* csr     = (int2*)(fill + N_NODES);
    int* bsum     = (int*)(csr + N_EDGES);
    __half* wbt   = (__half*)(bsum + 256);   // 5 x 65536 B f16 GEMM panels

    // d_out (102.4 MB): xlr16 [N][256] f16 (51.2) | ea16 [E][8] f16 (25.6)
    __half* xlr16 = (__half*)out;
    __half* ea16  = xlr16 + (size_t)N_NODES * 256;

    const int* srcv = ei;
    const int* dstv = ei + N_EDGES;

    hipMemsetAsync(fill, 0, N_NODES * sizeof(int), stream);
    hist_kernel<<<(N_EDGES + 255) / 256, 256, 0, stream>>>(dstv, fill);
    int nb = (N_NODES + 1023) / 1024;
    scan1_kernel<<<nb, 256, 0, stream>>>(fill, bsum);
    scan2_kernel<<<1, 256, 0, stream>>>(bsum, rowptr, nb);
    scan3_kernel<<<nb, 256, 0, stream>>>(fill, bsum, rowptr);
    hipMemsetAsync(fill, 0, N_NODES * sizeof(int), stream);
    fill_kernel<<<(N_EDGES + 255) / 256, 256, 0, stream>>>(srcv, dstv, rowptr, fill, csr);
    ecvt_kernel<<<(N_EDGES * 8 + 255) / 256, 256, 0, stream>>>(eattr, ea16);
    lattr_kernel<<<(N_NODES * 8 + 255) / 256, 256, 0, stream>>>(rowptr, csr, ea16, lat16);

    convw_kernel<<<(5 * 256 * 128 + 255) / 256, 256, 0, stream>>>(W_l, W_r, W_out, wbt);
    in_kernel<<<(N_NODES * HID) / 256, 256, 0, stream>>>(x, W_in, b_in, h16);

    for (int l = 0; l < LAYERS; ++l) {
        gemm_kernel<0><<<GRID_GEMM, 256, 0, stream>>>(
            h16, wbt + (size_t)l * 32768, b_l + (size_t)l * HID, b_r + (size_t)l * HID,
            xlr16, nullptr);
        edge_kernel<<<N_NODES, 64, 0, stream>>>(
            xlr16, h16, rowptr, csr, ea16, lat16,
            W_e + (size_t)l * ED_F * HID, att + (size_t)l * HEADS * CHN,
            bias + (size_t)l * HID, lnw + (size_t)l * HID, lnb + (size_t)l * HID);
    }

    gemm_kernel<1><<<GRID_GEMM, 256, 0, stream>>>(
        h16, wbt + (size_t)4 * 32768, b_out, nullptr, nullptr, out);
}